// Round 8
// baseline (272.721 us; speedup 1.0000x reference)
//
#include <hip/hip_runtime.h>
#include <hip/hip_bf16.h>
#include <math.h>

#define NN 50000
#define DD 128
#define CC 64
#define EE 800000
#define IND 384

typedef __attribute__((ext_vector_type(8))) short s8v;
typedef __attribute__((ext_vector_type(8))) unsigned short u8v;
typedef __attribute__((ext_vector_type(8))) float f8v;
typedef __attribute__((ext_vector_type(4))) float f4v;

static __device__ __forceinline__ unsigned short f2bf(float f) {
  __hip_bfloat16 b = __float2bfloat16(f);
  return *reinterpret_cast<unsigned short*>(&b);
}
static __device__ __forceinline__ float bf2f(unsigned short u) {
  __hip_bfloat16 b = *reinterpret_cast<__hip_bfloat16*>(&u);
  return __bfloat162float(b);
}
static __device__ __forceinline__ float blo(unsigned int u) {
  return __uint_as_float(u << 16);
}
static __device__ __forceinline__ float bhi(unsigned int u) {
  return __uint_as_float(u & 0xffff0000u);
}
static __device__ __forceinline__ s8v zero8() {
  s8v v = {0, 0, 0, 0, 0, 0, 0, 0};
  return v;
}

// ---------------- edge in-degree count ----------------
__global__ __launch_bounds__(256) void k_count(const int* __restrict__ dst,
                                               int* __restrict__ cnt) {
  int e = blockIdx.x * 256 + threadIdx.x;
  if (e < EE) atomicAdd(&cnt[dst[e]], 1);
}

// ---------------- hierarchical exclusive scan ----------------
__global__ __launch_bounds__(1024) void k_scan1(const int* __restrict__ cnt,
                                                int* __restrict__ rowstart,
                                                float* __restrict__ dinv,
                                                int* __restrict__ bsum) {
  __shared__ int wsum[16];
  int tid = threadIdx.x;
  int wave = tid >> 6, lane = tid & 63;
  int i = blockIdx.x * 1024 + tid;
  int v = (i < NN) ? cnt[i] : 0;
  int x = v;
#pragma unroll
  for (int off = 1; off < 64; off <<= 1) {
    int t = __shfl_up(x, off);
    if (lane >= off) x += t;
  }
  if (lane == 63) wsum[wave] = x;
  __syncthreads();
  if (wave == 0 && lane < 16) {
    int y = wsum[lane];
#pragma unroll
    for (int off = 1; off < 16; off <<= 1) {
      int t = __shfl_up(y, off);
      if (lane >= off) y += t;
    }
    wsum[lane] = y;
  }
  __syncthreads();
  int ex = (wave ? wsum[wave - 1] : 0) + x - v;
  if (i < NN) {
    rowstart[i] = ex;
    dinv[i] = 1.0f / sqrtf((float)(v + 1));
  }
  if (tid == 1023) bsum[blockIdx.x] = wsum[15];
}

__global__ __launch_bounds__(64) void k_scan2(int* __restrict__ bsum,
                                              int* __restrict__ rowstart,
                                              int nb) {
  int lane = threadIdx.x;
  int v = (lane < nb) ? bsum[lane] : 0;
  int x = v;
#pragma unroll
  for (int off = 1; off < 64; off <<= 1) {
    int t = __shfl_up(x, off);
    if (lane >= off) x += t;
  }
  if (lane < nb) bsum[lane] = x - v;
  if (lane == 0) rowstart[NN] = EE;
}

__global__ __launch_bounds__(1024) void k_scan3(int* __restrict__ rowstart,
                                                int* __restrict__ cursor,
                                                const int* __restrict__ bsum) {
  int i = blockIdx.x * 1024 + threadIdx.x;
  if (i < NN) {
    int r = rowstart[i] + bsum[blockIdx.x];
    rowstart[i] = r;
    cursor[i] = r;
  }
}

// ---------------- CSR placement ----------------
__global__ __launch_bounds__(256) void k_place(const int* __restrict__ src,
                                               const int* __restrict__ dst,
                                               int* __restrict__ cursor,
                                               int* __restrict__ col) {
  int e = blockIdx.x * 256 + threadIdx.x;
  if (e < EE) {
    int d = dst[e];
    int p = atomicAdd(&cursor[d], 1);
    col[p] = src[e];
  }
}

// ---- per-node logmap scales, with dinv folded in: sc1=dinv*ch, sc2=dinv*cs ----
__global__ __launch_bounds__(256) void k_scal(const float* __restrict__ xH,
                                              const float* __restrict__ xS,
                                              const float* __restrict__ dinv,
                                              float* __restrict__ sc1,
                                              float* __restrict__ sc2) {
  int gw = (blockIdx.x * 256 + threadIdx.x) >> 6;
  int lane = threadIdx.x & 63;
  if (gw >= NN) return;
  const float2* h2 = (const float2*)(xH) + (size_t)gw * 64;
  float2 vh = h2[lane];
  float ssh = vh.x * vh.x + vh.y * vh.y;
  if (lane == 0) ssh -= vh.x * vh.x;  // exclude element 0 (direct sum of x[1:])
#pragma unroll
  for (int off = 32; off; off >>= 1) ssh += __shfl_down(ssh, off);
  const float2* s2 = (const float2*)(xS) + (size_t)gw * 64;
  float2 vs = s2[lane];
  float sss = vs.x * vs.x + vs.y * vs.y;
  if (lane == 0) sss -= vs.x * vs.x;
#pragma unroll
  for (int off = 32; off; off >>= 1) sss += __shfl_down(sss, off);
  if (lane == 0) {
    float dv = dinv[gw];
    float nrh = sqrtf(ssh);
    float dist = acoshf(fmaxf(vh.x, 1.0f));
    sc1[gw] = dv * dist / fmaxf(nrh, 1e-12f);
    float nrs = sqrtf(sss);
    float th = acosf(fminf(fmaxf(vs.x, -1.0f), 1.0f));
    sc2[gw] = dv * th / fmaxf(nrs, 1e-12f);
  }
}

// ---------------- W transpose + bf16 hi/lo split: Wt[128][384] ----------------
__global__ __launch_bounds__(256) void k_wprep(const float* __restrict__ W,
                                               unsigned short* __restrict__ Wth,
                                               unsigned short* __restrict__ Wtl) {
  int flat = blockIdx.x * 256 + threadIdx.x;
  if (flat >= IND * DD) return;
  int n = flat / IND;
  int k = flat - n * IND;
  float v = W[(size_t)k * DD + n];
  unsigned short hi = f2bf(v);
  unsigned short lo = f2bf(v - bf2f(hi));
  Wth[(size_t)n * IND + k] = hi;
  Wtl[(size_t)n * IND + k] = lo;
}

// ---- MFMA GEMM, streaming register pipeline ----
// 1-wave (64-thread) blocks; wave tile = 16 rows x 64 cols; grid 3125x2.
// Input pre-scaled by dinv (and logmap scale for H/S sections) -> h = dinv*x@W.
// No LDS, no barriers, no cross-lane ops: every (sec,q) step is independent:
// 32B A-load -> scale -> bf16 hi/lo split -> 8 coalesced B loads -> 24 MFMA.
__global__ __launch_bounds__(64, 4) void k_gemm(const float* __restrict__ xE,
                                                const float* __restrict__ xH,
                                                const float* __restrict__ xS,
                                                const float* __restrict__ dinv,
                                                const float* __restrict__ sc1,
                                                const float* __restrict__ sc2,
                                                const unsigned short* __restrict__ Wth,
                                                const unsigned short* __restrict__ Wtl,
                                                unsigned short* __restrict__ h) {
  int lane = threadIdx.x;
  int bid = blockIdx.x;
  int rowt = bid >> 1;         // 0..3124 (50000 = 3125*16, no bounds checks)
  int wc = bid & 1;
  int c0 = wc * 64;
  int l15 = lane & 15;
  int lhi = lane >> 4;
  int node = rowt * 16 + l15;
  size_t rowbase = (size_t)node * DD;

  f4v acc[4];
#pragma unroll
  for (int nf = 0; nf < 4; ++nf) acc[nf] = f4v{0.f, 0.f, 0.f, 0.f};

#pragma unroll
  for (int sec = 0; sec < 3; ++sec) {
    const float* __restrict__ src = (sec == 0) ? xE : (sec == 1) ? xH : xS;
    float scl = (sec == 0) ? dinv[node] : (sec == 1) ? sc1[node] : sc2[node];
#pragma unroll
    for (int q = 0; q < 4; ++q) {
      f8v v = *reinterpret_cast<const f8v*>(&src[rowbase + q * 32 + lhi * 8]);
      u8v hh, ll;
#pragma unroll
      for (int j = 0; j < 8; ++j) {
        float t = v[j] * scl;
        if (sec > 0 && q == 0 && j == 0 && lhi == 0) t = 0.f;  // logmap zero col
        unsigned short hi = f2bf(t);
        hh[j] = hi;
        ll[j] = f2bf(t - bf2f(hi));
      }
      s8v ah = *reinterpret_cast<s8v*>(&hh);
      s8v al = *reinterpret_cast<s8v*>(&ll);
      int kk = sec * 128 + q * 32 + lhi * 8;
#pragma unroll
      for (int nf = 0; nf < 4; ++nf) {
        int n = c0 + nf * 16 + l15;
        s8v bh = *reinterpret_cast<const s8v*>(&Wth[(size_t)n * IND + kk]);
        s8v bl = *reinterpret_cast<const s8v*>(&Wtl[(size_t)n * IND + kk]);
        acc[nf] = __builtin_amdgcn_mfma_f32_16x16x32_bf16(ah, bh, acc[nf], 0, 0, 0);
        acc[nf] = __builtin_amdgcn_mfma_f32_16x16x32_bf16(al, bh, acc[nf], 0, 0, 0);
        acc[nf] = __builtin_amdgcn_mfma_f32_16x16x32_bf16(ah, bl, acc[nf], 0, 0, 0);
      }
    }
  }
  int rowb = rowt * 16 + lhi * 4;
#pragma unroll
  for (int nf = 0; nf < 4; ++nf) {
    int colx = c0 + nf * 16 + l15;
#pragma unroll
    for (int j = 0; j < 4; ++j)
      h[(size_t)(rowb + j) * DD + colx] = f2bf(acc[nf][j]);
  }
}

// ---------------- normalize class embeddings -> bf16 hi/lo [64][128] ----------
__global__ __launch_bounds__(256) void k_cprep(const float* __restrict__ cls,
                                               unsigned int* __restrict__ clsh,
                                               unsigned int* __restrict__ clsl) {
  int wave = threadIdx.x >> 6, lane = threadIdx.x & 63;
  for (int c = wave; c < CC; c += 4) {
    const float2* r2 = (const float2*)(cls + (size_t)c * DD);
    float2 v = r2[lane];
    float ss = v.x * v.x + v.y * v.y;
#pragma unroll
    for (int off = 32; off; off >>= 1) ss += __shfl_xor(ss, off);
    float inv = 1.0f / fmaxf(sqrtf(ss), 1e-8f);
    float nx = v.x * inv, ny = v.y * inv;
    unsigned short hx = f2bf(nx), hy = f2bf(ny);
    unsigned short lx = f2bf(nx - bf2f(hx)), ly = f2bf(ny - bf2f(hy));
    clsh[c * 64 + lane] = (unsigned int)hx | ((unsigned int)hy << 16);
    clsl[c * 64 + lane] = (unsigned int)lx | ((unsigned int)ly << 16);
  }
}

// ---- CSR aggregation (h pre-scaled by dinv) + normalize -> xn bf16 hi/lo ----
__global__ __launch_bounds__(256) void k_aggn(const unsigned short* __restrict__ h,
                                              const int* __restrict__ rowstart,
                                              const int* __restrict__ col,
                                              const float* __restrict__ dinv,
                                              const float* __restrict__ b,
                                              unsigned int* __restrict__ xnh,
                                              unsigned int* __restrict__ xnl) {
  int node = (blockIdx.x * 256 + threadIdx.x) >> 6;
  int lane = threadIdx.x & 63;
  if (node >= NN) return;

  const unsigned int* h2 = (const unsigned int*)h;
  float dv = dinv[node];
  unsigned int hv = h2[(size_t)node * 64 + lane];  // = dinv[node]*h[node]
  float ax = blo(hv), ay = bhi(hv);
  int s = rowstart[node], e = rowstart[node + 1];
  int j = s;
  for (; j + 15 < e; j += 16) {
    int cc[16];
    unsigned int vv[16];
#pragma unroll
    for (int q = 0; q < 16; ++q) cc[q] = col[j + q];
#pragma unroll
    for (int q = 0; q < 16; ++q) vv[q] = h2[(size_t)cc[q] * 64 + lane];
#pragma unroll
    for (int q = 0; q < 16; ++q) {
      ax += blo(vv[q]);
      ay += bhi(vv[q]);
    }
  }
  for (; j + 3 < e; j += 4) {
    int c0_ = col[j], c1_ = col[j + 1], c2_ = col[j + 2], c3_ = col[j + 3];
    unsigned int v0 = h2[(size_t)c0_ * 64 + lane];
    unsigned int v1 = h2[(size_t)c1_ * 64 + lane];
    unsigned int v2 = h2[(size_t)c2_ * 64 + lane];
    unsigned int v3 = h2[(size_t)c3_ * 64 + lane];
    ax += blo(v0) + blo(v1) + blo(v2) + blo(v3);
    ay += bhi(v0) + bhi(v1) + bhi(v2) + bhi(v3);
  }
  for (; j < e; ++j) {
    unsigned int v = h2[(size_t)col[j] * 64 + lane];
    ax += blo(v);
    ay += bhi(v);
  }
  const float2* b2 = (const float2*)b;
  float2 bb = b2[lane];
  float rx = dv * ax + bb.x;
  float ry = dv * ay + bb.y;
  float ss = rx * rx + ry * ry;
#pragma unroll
  for (int off = 32; off; off >>= 1) ss += __shfl_xor(ss, off);
  float inv = 1.0f / fmaxf(sqrtf(ss), 1e-8f);
  float nx = rx * inv, ny = ry * inv;
  unsigned short hx = f2bf(nx), hy = f2bf(ny);
  unsigned short lx = f2bf(nx - bf2f(hx)), ly = f2bf(ny - bf2f(hy));
  xnh[(size_t)node * 64 + lane] = (unsigned int)hx | ((unsigned int)hy << 16);
  xnl[(size_t)node * 64 + lane] = (unsigned int)lx | ((unsigned int)ly << 16);
}

// ---- classifier MFMA GEMM: out = xn @ clsn^T (hi/lo 3-term) ----
__global__ __launch_bounds__(256) void k_outg(const unsigned short* __restrict__ xnh,
                                              const unsigned short* __restrict__ xnl,
                                              const unsigned short* __restrict__ clsh,
                                              const unsigned short* __restrict__ clsl,
                                              float* __restrict__ out) {
  int tid = threadIdx.x;
  int lane = tid & 63;
  int wid = tid >> 6;
  int l15 = lane & 15, lhi = lane >> 4;
  int bm0 = blockIdx.x * 128 + wid * 32;

  f4v acc[2][4];
#pragma unroll
  for (int m = 0; m < 2; ++m)
#pragma unroll
    for (int nf = 0; nf < 4; ++nf) acc[m][nf] = f4v{0.f, 0.f, 0.f, 0.f};

#pragma unroll
  for (int ks = 0; ks < 4; ++ks) {
    s8v ah[2], al[2];
#pragma unroll
    for (int m = 0; m < 2; ++m) {
      int row = bm0 + m * 16 + l15;
      if (row < NN) {
        ah[m] = *reinterpret_cast<const s8v*>(&xnh[(size_t)row * DD + ks * 32 + lhi * 8]);
        al[m] = *reinterpret_cast<const s8v*>(&xnl[(size_t)row * DD + ks * 32 + lhi * 8]);
      } else {
        ah[m] = zero8();
        al[m] = zero8();
      }
    }
#pragma unroll
    for (int nf = 0; nf < 4; ++nf) {
      int n = nf * 16 + l15;
      s8v bh = *reinterpret_cast<const s8v*>(&clsh[(size_t)n * DD + ks * 32 + lhi * 8]);
      s8v bl = *reinterpret_cast<const s8v*>(&clsl[(size_t)n * DD + ks * 32 + lhi * 8]);
#pragma unroll
      for (int m = 0; m < 2; ++m) {
        acc[m][nf] = __builtin_amdgcn_mfma_f32_16x16x32_bf16(ah[m], bh, acc[m][nf], 0, 0, 0);
        acc[m][nf] = __builtin_amdgcn_mfma_f32_16x16x32_bf16(al[m], bh, acc[m][nf], 0, 0, 0);
        acc[m][nf] = __builtin_amdgcn_mfma_f32_16x16x32_bf16(ah[m], bl, acc[m][nf], 0, 0, 0);
      }
    }
  }
#pragma unroll
  for (int m = 0; m < 2; ++m)
#pragma unroll
    for (int nf = 0; nf < 4; ++nf) {
      int colx = nf * 16 + l15;
      int rowb = bm0 + m * 16 + lhi * 4;
#pragma unroll
      for (int j = 0; j < 4; ++j) {
        int row = rowb + j;
        if (row < NN) out[(size_t)row * CC + colx] = acc[m][nf][j];
      }
    }
}

extern "C" void kernel_launch(void* const* d_in, const int* in_sizes, int n_in,
                              void* d_out, int out_size, void* d_ws, size_t ws_size,
                              hipStream_t stream) {
  const float* xE = (const float*)d_in[0];
  const float* xH = (const float*)d_in[1];
  const float* xS = (const float*)d_in[2];
  const int* ei = (const int*)d_in[3];
  const float* W = (const float*)d_in[4];
  const float* b = (const float*)d_in[5];
  const float* cls = (const float*)d_in[6];
  float* out = (float*)d_out;

  char* ws = (char*)d_ws;
  size_t off = 0;
  auto alloc = [&](size_t bytes) {
    void* p = ws + off;
    off = (off + bytes + 255) & ~(size_t)255;
    return p;
  };
  unsigned short* h = (unsigned short*)alloc((size_t)NN * DD * 2);
  unsigned int* xnh = (unsigned int*)alloc((size_t)NN * 64 * 4);
  unsigned int* xnl = (unsigned int*)alloc((size_t)NN * 64 * 4);
  float* dinv = (float*)alloc((size_t)NN * 4);
  float* sc1 = (float*)alloc((size_t)NN * 4);
  float* sc2 = (float*)alloc((size_t)NN * 4);
  int* cnt = (int*)alloc((size_t)NN * 4);
  int* rowst = (int*)alloc((size_t)(NN + 1) * 4);
  int* cursor = (int*)alloc((size_t)NN * 4);
  int* col = (int*)alloc((size_t)EE * 4);
  unsigned short* Wth = (unsigned short*)alloc((size_t)DD * IND * 2);
  unsigned short* Wtl = (unsigned short*)alloc((size_t)DD * IND * 2);
  unsigned int* clsh = (unsigned int*)alloc((size_t)CC * 64 * 4);
  unsigned int* clsl = (unsigned int*)alloc((size_t)CC * 64 * 4);
  int* bsum = (int*)alloc(64 * 4);

  const int* esrc = ei;
  const int* edst = ei + EE;
  const int NB = (NN + 1023) / 1024;

  hipMemsetAsync(cnt, 0, (size_t)NN * 4, stream);
  k_count<<<(EE + 255) / 256, 256, 0, stream>>>(edst, cnt);
  k_scan1<<<NB, 1024, 0, stream>>>(cnt, rowst, dinv, bsum);
  k_scan2<<<1, 64, 0, stream>>>(bsum, rowst, NB);
  k_scan3<<<NB, 1024, 0, stream>>>(rowst, cursor, bsum);
  k_place<<<(EE + 255) / 256, 256, 0, stream>>>(esrc, edst, cursor, col);
  k_wprep<<<(IND * DD + 255) / 256, 256, 0, stream>>>(W, Wth, Wtl);
  k_cprep<<<1, 256, 0, stream>>>(cls, clsh, clsl);
  k_scal<<<(NN + 3) / 4, 256, 0, stream>>>(xH, xS, dinv, sc1, sc2);
  k_gemm<<<(NN / 16) * 2, 64, 0, stream>>>(xE, xH, xS, dinv, sc1, sc2, Wth, Wtl, h);
  k_aggn<<<(NN + 3) / 4, 256, 0, stream>>>(h, rowst, col, dinv, b, xnh, xnl);
  k_outg<<<(NN + 127) / 128, 256, 0, stream>>>((const unsigned short*)xnh,
                                               (const unsigned short*)xnl,
                                               (const unsigned short*)clsh,
                                               (const unsigned short*)clsl, out);
}

// Round 9
// 214.054 us; speedup vs baseline: 1.2741x; 1.2741x over previous
//
#include <hip/hip_runtime.h>
#include <hip/hip_fp16.h>
#include <math.h>

#define NN 50000
#define DD 128
#define CC 64
#define EE 800000
#define IND 384

typedef __attribute__((ext_vector_type(8))) _Float16 h8v;
typedef __attribute__((ext_vector_type(4))) float f4v;

static __device__ __forceinline__ unsigned short f2h(float f) {
  _Float16 h = (_Float16)f;
  return *reinterpret_cast<unsigned short*>(&h);
}
static __device__ __forceinline__ float h2f(unsigned short u) {
  _Float16 h = *reinterpret_cast<_Float16*>(&u);
  return (float)h;
}
static __device__ __forceinline__ float hlo(unsigned int u) {
  return h2f((unsigned short)(u & 0xffffu));
}
static __device__ __forceinline__ float hhi(unsigned int u) {
  return h2f((unsigned short)(u >> 16));
}
static __device__ __forceinline__ h8v hzero() {
  h8v v = {0, 0, 0, 0, 0, 0, 0, 0};
  return v;
}

// ---------------- edge in-degree count ----------------
__global__ __launch_bounds__(256) void k_count(const int* __restrict__ dst,
                                               int* __restrict__ cnt) {
  int e = blockIdx.x * 256 + threadIdx.x;
  if (e < EE) atomicAdd(&cnt[dst[e]], 1);
}

// ---------------- hierarchical exclusive scan ----------------
__global__ __launch_bounds__(1024) void k_scan1(const int* __restrict__ cnt,
                                                int* __restrict__ rowstart,
                                                float* __restrict__ dinv,
                                                int* __restrict__ bsum) {
  __shared__ int wsum[16];
  int tid = threadIdx.x;
  int wave = tid >> 6, lane = tid & 63;
  int i = blockIdx.x * 1024 + tid;
  int v = (i < NN) ? cnt[i] : 0;
  int x = v;
#pragma unroll
  for (int off = 1; off < 64; off <<= 1) {
    int t = __shfl_up(x, off);
    if (lane >= off) x += t;
  }
  if (lane == 63) wsum[wave] = x;
  __syncthreads();
  if (wave == 0 && lane < 16) {
    int y = wsum[lane];
#pragma unroll
    for (int off = 1; off < 16; off <<= 1) {
      int t = __shfl_up(y, off);
      if (lane >= off) y += t;
    }
    wsum[lane] = y;
  }
  __syncthreads();
  int ex = (wave ? wsum[wave - 1] : 0) + x - v;
  if (i < NN) {
    rowstart[i] = ex;
    dinv[i] = 1.0f / sqrtf((float)(v + 1));
  }
  if (tid == 1023) bsum[blockIdx.x] = wsum[15];
}

__global__ __launch_bounds__(64) void k_scan2(int* __restrict__ bsum,
                                              int* __restrict__ rowstart,
                                              int nb) {
  int lane = threadIdx.x;
  int v = (lane < nb) ? bsum[lane] : 0;
  int x = v;
#pragma unroll
  for (int off = 1; off < 64; off <<= 1) {
    int t = __shfl_up(x, off);
    if (lane >= off) x += t;
  }
  if (lane < nb) bsum[lane] = x - v;
  if (lane == 0) rowstart[NN] = EE;
}

__global__ __launch_bounds__(1024) void k_scan3(int* __restrict__ rowstart,
                                                int* __restrict__ cursor,
                                                const int* __restrict__ bsum) {
  int i = blockIdx.x * 1024 + threadIdx.x;
  if (i < NN) {
    int r = rowstart[i] + bsum[blockIdx.x];
    rowstart[i] = r;
    cursor[i] = r;
  }
}

// ---------------- CSR placement ----------------
__global__ __launch_bounds__(256) void k_place(const int* __restrict__ src,
                                               const int* __restrict__ dst,
                                               int* __restrict__ cursor,
                                               int* __restrict__ col) {
  int e = blockIdx.x * 256 + threadIdx.x;
  if (e < EE) {
    int d = dst[e];
    int p = atomicAdd(&cursor[d], 1);
    col[p] = src[e];
  }
}

// ---- per-node logmap scales with dinv folded: sc1=dinv*ch, sc2=dinv*cs ----
__global__ __launch_bounds__(256) void k_scal(const float* __restrict__ xH,
                                              const float* __restrict__ xS,
                                              const float* __restrict__ dinv,
                                              float* __restrict__ sc1,
                                              float* __restrict__ sc2) {
  int gw = (blockIdx.x * 256 + threadIdx.x) >> 6;
  int lane = threadIdx.x & 63;
  if (gw >= NN) return;
  const float2* h2 = (const float2*)(xH) + (size_t)gw * 64;
  float2 vh = h2[lane];
  float ssh = vh.x * vh.x + vh.y * vh.y;
  if (lane == 0) ssh -= vh.x * vh.x;  // direct sum over x[1:]
#pragma unroll
  for (int off = 32; off; off >>= 1) ssh += __shfl_down(ssh, off);
  const float2* s2 = (const float2*)(xS) + (size_t)gw * 64;
  float2 vs = s2[lane];
  float sss = vs.x * vs.x + vs.y * vs.y;
  if (lane == 0) sss -= vs.x * vs.x;
#pragma unroll
  for (int off = 32; off; off >>= 1) sss += __shfl_down(sss, off);
  if (lane == 0) {
    float dv = dinv[gw];
    float nrh = sqrtf(ssh);
    float dist = acoshf(fmaxf(vh.x, 1.0f));
    sc1[gw] = dv * dist / fmaxf(nrh, 1e-12f);
    float nrs = sqrtf(sss);
    float th = acosf(fminf(fmaxf(vs.x, -1.0f), 1.0f));
    sc2[gw] = dv * th / fmaxf(nrs, 1e-12f);
  }
}

// ---------------- W transpose + fp16: Wt[128][384] ----------------
__global__ __launch_bounds__(256) void k_wprep(const float* __restrict__ W,
                                               unsigned short* __restrict__ Wt) {
  int flat = blockIdx.x * 256 + threadIdx.x;
  if (flat >= IND * DD) return;
  int n = flat / IND;
  int k = flat - n * IND;
  Wt[(size_t)n * IND + k] = f2h(W[(size_t)k * DD + n]);
}

// ---- MFMA fp16 GEMM: h = dinv * ([xE | ch*xH | cs*xS] @ W), fp16 out ----
// block 64 rows x 128 cols, 4 waves 2x2; wave = 32r x 64c. LDS A fp16 8KB,
// XOR-swizzled; single-term fp16 MFMA (96/wave), B from L2 (96KB Wt).
__global__ __launch_bounds__(256) void k_gemm(const float* __restrict__ xE,
                                              const float* __restrict__ xH,
                                              const float* __restrict__ xS,
                                              const float* __restrict__ dinv,
                                              const float* __restrict__ sc1,
                                              const float* __restrict__ sc2,
                                              const unsigned short* __restrict__ Wt,
                                              unsigned short* __restrict__ h) {
  __shared__ unsigned short Ah[64 * 64];  // 8 KB
  int tid = threadIdx.x;
  int lane = tid & 63;
  int wid = tid >> 6;
  int wr = wid >> 1, wc = wid & 1;
  int r0 = wr * 32, c0 = wc * 64;
  int bm0 = blockIdx.x * 64;
  int l15 = lane & 15;
  int lhi = lane >> 4;

  f4v acc[2][4];
#pragma unroll
  for (int m = 0; m < 2; ++m)
#pragma unroll
    for (int nf = 0; nf < 4; ++nf) acc[m][nf] = f4v{0.f, 0.f, 0.f, 0.f};

  for (int kb = 0; kb < IND; kb += 64) {
    int sec = kb >> 7;
    int off = kb & 127;
    const float* __restrict__ src = (sec == 0) ? xE : (sec == 1) ? xH : xS;
#pragma unroll
    for (int it = 0; it < 4; ++it) {
      int flat = tid + it * 256;
      int row = flat >> 4;
      int f4 = flat & 15;
      int node = bm0 + row;
      float4 v = make_float4(0.f, 0.f, 0.f, 0.f);
      float scale = 0.f;
      if (node < NN) {
        v = *(const float4*)&src[(size_t)node * DD + off + f4 * 4];
        scale = (sec == 0) ? dinv[node] : (sec == 1) ? sc1[node] : sc2[node];
      }
      v.x *= scale; v.y *= scale; v.z *= scale; v.w *= scale;
      if (sec > 0 && off == 0 && f4 == 0) v.x = 0.f;  // logmap zero column
      ushort4 o;
      o.x = f2h(v.x); o.y = f2h(v.y); o.z = f2h(v.z); o.w = f2h(v.w);
      int idx = (row * 64 + f4 * 4) ^ ((row & 7) << 3);
      *(ushort4*)&Ah[idx] = o;
    }
    __syncthreads();
#pragma unroll
    for (int ks = 0; ks < 2; ++ks) {
      h8v a[2];
#pragma unroll
      for (int m = 0; m < 2; ++m) {
        int row = r0 + m * 16 + l15;
        int idx = (row * 64 + ks * 32 + lhi * 8) ^ ((row & 7) << 3);
        a[m] = *reinterpret_cast<const h8v*>(&Ah[idx]);
      }
      int kk = kb + ks * 32 + lhi * 8;
#pragma unroll
      for (int nf = 0; nf < 4; ++nf) {
        int n = c0 + nf * 16 + l15;
        h8v b = *reinterpret_cast<const h8v*>(&Wt[(size_t)n * IND + kk]);
#pragma unroll
        for (int m = 0; m < 2; ++m)
          acc[m][nf] = __builtin_amdgcn_mfma_f32_16x16x32_f16(a[m], b, acc[m][nf], 0, 0, 0);
      }
    }
    __syncthreads();
  }
#pragma unroll
  for (int m = 0; m < 2; ++m)
#pragma unroll
    for (int nf = 0; nf < 4; ++nf) {
      int colx = c0 + nf * 16 + l15;
      int rowb = bm0 + r0 + m * 16 + lhi * 4;
#pragma unroll
      for (int j = 0; j < 4; ++j) {
        int node = rowb + j;
        if (node < NN) h[(size_t)node * DD + colx] = f2h(acc[m][nf][j]);
      }
    }
}

// ---------------- normalize class embeddings -> packed fp16 [64][128] --------
__global__ __launch_bounds__(256) void k_cprep(const float* __restrict__ cls,
                                               unsigned int* __restrict__ clsp) {
  int wave = threadIdx.x >> 6, lane = threadIdx.x & 63;
  for (int c = wave; c < CC; c += 4) {
    const float2* r2 = (const float2*)(cls + (size_t)c * DD);
    float2 v = r2[lane];
    float ss = v.x * v.x + v.y * v.y;
#pragma unroll
    for (int off = 32; off; off >>= 1) ss += __shfl_xor(ss, off);
    float inv = 1.0f / fmaxf(sqrtf(ss), 1e-8f);
    clsp[c * 64 + lane] =
        (unsigned int)f2h(v.x * inv) | ((unsigned int)f2h(v.y * inv) << 16);
  }
}

// ---- CSR aggregation (h pre-scaled by dinv) + normalize -> xn fp16 ----
__global__ __launch_bounds__(256) void k_aggn(const unsigned short* __restrict__ h,
                                              const int* __restrict__ rowstart,
                                              const int* __restrict__ col,
                                              const float* __restrict__ dinv,
                                              const float* __restrict__ b,
                                              unsigned int* __restrict__ xn) {
  int node = (blockIdx.x * 256 + threadIdx.x) >> 6;
  int lane = threadIdx.x & 63;
  if (node >= NN) return;

  const unsigned int* h2 = (const unsigned int*)h;
  float dv = dinv[node];
  unsigned int hv = h2[(size_t)node * 64 + lane];
  float ax = hlo(hv), ay = hhi(hv);
  int s = rowstart[node], e = rowstart[node + 1];
  int j = s;
  for (; j + 15 < e; j += 16) {
    int cc[16];
    unsigned int vv[16];
#pragma unroll
    for (int q = 0; q < 16; ++q) cc[q] = col[j + q];
#pragma unroll
    for (int q = 0; q < 16; ++q) vv[q] = h2[(size_t)cc[q] * 64 + lane];
#pragma unroll
    for (int q = 0; q < 16; ++q) {
      ax += hlo(vv[q]);
      ay += hhi(vv[q]);
    }
  }
  for (; j + 3 < e; j += 4) {
    int c0_ = col[j], c1_ = col[j + 1], c2_ = col[j + 2], c3_ = col[j + 3];
    unsigned int v0 = h2[(size_t)c0_ * 64 + lane];
    unsigned int v1 = h2[(size_t)c1_ * 64 + lane];
    unsigned int v2 = h2[(size_t)c2_ * 64 + lane];
    unsigned int v3 = h2[(size_t)c3_ * 64 + lane];
    ax += hlo(v0) + hlo(v1) + hlo(v2) + hlo(v3);
    ay += hhi(v0) + hhi(v1) + hhi(v2) + hhi(v3);
  }
  for (; j < e; ++j) {
    unsigned int v = h2[(size_t)col[j] * 64 + lane];
    ax += hlo(v);
    ay += hhi(v);
  }
  const float2* b2 = (const float2*)b;
  float2 bb = b2[lane];
  float rx = dv * ax + bb.x;
  float ry = dv * ay + bb.y;
  float ss = rx * rx + ry * ry;
#pragma unroll
  for (int off = 32; off; off >>= 1) ss += __shfl_xor(ss, off);
  float inv = 1.0f / fmaxf(sqrtf(ss), 1e-8f);
  xn[(size_t)node * 64 + lane] =
      (unsigned int)f2h(rx * inv) | ((unsigned int)f2h(ry * inv) << 16);
}

// ---- classifier fp16 MFMA GEMM: out = xn @ clsn^T ----
__global__ __launch_bounds__(256) void k_outg(const unsigned short* __restrict__ xn,
                                              const unsigned short* __restrict__ clsp,
                                              float* __restrict__ out) {
  int tid = threadIdx.x;
  int lane = tid & 63;
  int wid = tid >> 6;
  int l15 = lane & 15, lhi = lane >> 4;
  int bm0 = blockIdx.x * 128 + wid * 32;

  f4v acc[2][4];
#pragma unroll
  for (int m = 0; m < 2; ++m)
#pragma unroll
    for (int nf = 0; nf < 4; ++nf) acc[m][nf] = f4v{0.f, 0.f, 0.f, 0.f};

#pragma unroll
  for (int ks = 0; ks < 4; ++ks) {
    h8v a[2];
#pragma unroll
    for (int m = 0; m < 2; ++m) {
      int row = bm0 + m * 16 + l15;
      a[m] = (row < NN)
                 ? *reinterpret_cast<const h8v*>(&xn[(size_t)row * DD + ks * 32 + lhi * 8])
                 : hzero();
    }
#pragma unroll
    for (int nf = 0; nf < 4; ++nf) {
      int n = nf * 16 + l15;
      h8v b = *reinterpret_cast<const h8v*>(&clsp[(size_t)n * DD + ks * 32 + lhi * 8]);
#pragma unroll
      for (int m = 0; m < 2; ++m)
        acc[m][nf] = __builtin_amdgcn_mfma_f32_16x16x32_f16(a[m], b, acc[m][nf], 0, 0, 0);
    }
  }
#pragma unroll
  for (int m = 0; m < 2; ++m)
#pragma unroll
    for (int nf = 0; nf < 4; ++nf) {
      int colx = nf * 16 + l15;
      int rowb = bm0 + m * 16 + lhi * 4;
#pragma unroll
      for (int j = 0; j < 4; ++j) {
        int row = rowb + j;
        if (row < NN) out[(size_t)row * CC + colx] = acc[m][nf][j];
      }
    }
}

extern "C" void kernel_launch(void* const* d_in, const int* in_sizes, int n_in,
                              void* d_out, int out_size, void* d_ws, size_t ws_size,
                              hipStream_t stream) {
  const float* xE = (const float*)d_in[0];
  const float* xH = (const float*)d_in[1];
  const float* xS = (const float*)d_in[2];
  const int* ei = (const int*)d_in[3];
  const float* W = (const float*)d_in[4];
  const float* b = (const float*)d_in[5];
  const float* cls = (const float*)d_in[6];
  float* out = (float*)d_out;

  char* ws = (char*)d_ws;
  size_t off = 0;
  auto alloc = [&](size_t bytes) {
    void* p = ws + off;
    off = (off + bytes + 255) & ~(size_t)255;
    return p;
  };
  unsigned short* h = (unsigned short*)alloc((size_t)NN * DD * 2);
  unsigned int* xn = (unsigned int*)alloc((size_t)NN * 64 * 4);
  float* dinv = (float*)alloc((size_t)NN * 4);
  float* sc1 = (float*)alloc((size_t)NN * 4);
  float* sc2 = (float*)alloc((size_t)NN * 4);
  int* cnt = (int*)alloc((size_t)NN * 4);
  int* rowst = (int*)alloc((size_t)(NN + 1) * 4);
  int* cursor = (int*)alloc((size_t)NN * 4);
  int* col = (int*)alloc((size_t)EE * 4);
  unsigned short* Wt = (unsigned short*)alloc((size_t)DD * IND * 2);
  unsigned int* clsp = (unsigned int*)alloc((size_t)CC * 64 * 4);
  int* bsum = (int*)alloc(64 * 4);

  const int* esrc = ei;
  const int* edst = ei + EE;
  const int NB = (NN + 1023) / 1024;

  hipMemsetAsync(cnt, 0, (size_t)NN * 4, stream);
  k_count<<<(EE + 255) / 256, 256, 0, stream>>>(edst, cnt);
  k_scan1<<<NB, 1024, 0, stream>>>(cnt, rowst, dinv, bsum);
  k_scan2<<<1, 64, 0, stream>>>(bsum, rowst, NB);
  k_scan3<<<NB, 1024, 0, stream>>>(rowst, cursor, bsum);
  k_place<<<(EE + 255) / 256, 256, 0, stream>>>(esrc, edst, cursor, col);
  k_wprep<<<(IND * DD + 255) / 256, 256, 0, stream>>>(W, Wt);
  k_cprep<<<1, 256, 0, stream>>>(cls, clsp);
  k_scal<<<(NN + 3) / 4, 256, 0, stream>>>(xH, xS, dinv, sc1, sc2);
  k_gemm<<<(NN + 63) / 64, 256, 0, stream>>>(xE, xH, xS, dinv, sc1, sc2, Wt, h);
  k_aggn<<<(NN + 3) / 4, 256, 0, stream>>>(h, rowst, col, dinv, b, xn);
  k_outg<<<(NN + 127) / 128, 256, 0, stream>>>((const unsigned short*)xn,
                                               (const unsigned short*)clsp, out);
}

// Round 10
// 172.297 us; speedup vs baseline: 1.5829x; 1.2424x over previous
//
#include <hip/hip_runtime.h>
#include <hip/hip_fp16.h>
#include <math.h>

#define NN 50000
#define DD 128
#define CC 64
#define EE 800000
#define IND 384

typedef __attribute__((ext_vector_type(8))) _Float16 h8v;
typedef __attribute__((ext_vector_type(4))) float f4v;

static __device__ __forceinline__ unsigned short f2h(float f) {
  _Float16 h = (_Float16)f;
  return *reinterpret_cast<unsigned short*>(&h);
}
static __device__ __forceinline__ float h2f(unsigned short u) {
  _Float16 h = *reinterpret_cast<_Float16*>(&u);
  return (float)h;
}
static __device__ __forceinline__ float hlo(unsigned int u) {
  return h2f((unsigned short)(u & 0xffffu));
}
static __device__ __forceinline__ float hhi(unsigned int u) {
  return h2f((unsigned short)(u >> 16));
}
static __device__ __forceinline__ h8v hzero() {
  h8v v = {0, 0, 0, 0, 0, 0, 0, 0};
  return v;
}

// ---- edge in-degree count + per-edge rank (atomic return value) ----
__global__ __launch_bounds__(256) void k_count(const int* __restrict__ dst,
                                               int* __restrict__ cnt,
                                               int* __restrict__ rank) {
  int e = blockIdx.x * 256 + threadIdx.x;
  if (e < EE) rank[e] = atomicAdd(&cnt[dst[e]], 1);
}

// ---------------- hierarchical exclusive scan ----------------
__global__ __launch_bounds__(1024) void k_scan1(const int* __restrict__ cnt,
                                                int* __restrict__ rowstart,
                                                float* __restrict__ dinv,
                                                int* __restrict__ bsum) {
  __shared__ int wsum[16];
  int tid = threadIdx.x;
  int wave = tid >> 6, lane = tid & 63;
  int i = blockIdx.x * 1024 + tid;
  int v = (i < NN) ? cnt[i] : 0;
  int x = v;
#pragma unroll
  for (int off = 1; off < 64; off <<= 1) {
    int t = __shfl_up(x, off);
    if (lane >= off) x += t;
  }
  if (lane == 63) wsum[wave] = x;
  __syncthreads();
  if (wave == 0 && lane < 16) {
    int y = wsum[lane];
#pragma unroll
    for (int off = 1; off < 16; off <<= 1) {
      int t = __shfl_up(y, off);
      if (lane >= off) y += t;
    }
    wsum[lane] = y;
  }
  __syncthreads();
  int ex = (wave ? wsum[wave - 1] : 0) + x - v;
  if (i < NN) {
    rowstart[i] = ex;
    dinv[i] = 1.0f / sqrtf((float)(v + 1));
  }
  if (tid == 1023) bsum[blockIdx.x] = wsum[15];
}

__global__ __launch_bounds__(64) void k_scan2(int* __restrict__ bsum,
                                              int* __restrict__ rowstart,
                                              int nb) {
  int lane = threadIdx.x;
  int v = (lane < nb) ? bsum[lane] : 0;
  int x = v;
#pragma unroll
  for (int off = 1; off < 64; off <<= 1) {
    int t = __shfl_up(x, off);
    if (lane >= off) x += t;
  }
  if (lane < nb) bsum[lane] = x - v;
  if (lane == 0) rowstart[NN] = EE;
}

__global__ __launch_bounds__(1024) void k_scan3(int* __restrict__ rowstart,
                                                const int* __restrict__ bsum) {
  int i = blockIdx.x * 1024 + threadIdx.x;
  if (i < NN) rowstart[i] += bsum[blockIdx.x];
}

// ---- CSR placement, atomic-free: p = rowstart[dst] + rank ----
__global__ __launch_bounds__(256) void k_place(const int* __restrict__ src,
                                               const int* __restrict__ dst,
                                               const int* __restrict__ rank,
                                               const int* __restrict__ rowstart,
                                               int* __restrict__ col) {
  int e = blockIdx.x * 256 + threadIdx.x;
  if (e < EE) {
    int d = dst[e];
    col[rowstart[d] + rank[e]] = src[e];
  }
}

// ---- per-node logmap scales with dinv folded: sc1=dinv*ch, sc2=dinv*cs ----
__global__ __launch_bounds__(256) void k_scal(const float* __restrict__ xH,
                                              const float* __restrict__ xS,
                                              const float* __restrict__ dinv,
                                              float* __restrict__ sc1,
                                              float* __restrict__ sc2) {
  int gw = (blockIdx.x * 256 + threadIdx.x) >> 6;
  int lane = threadIdx.x & 63;
  if (gw >= NN) return;
  const float2* h2 = (const float2*)(xH) + (size_t)gw * 64;
  float2 vh = h2[lane];
  float ssh = vh.x * vh.x + vh.y * vh.y;
  if (lane == 0) ssh -= vh.x * vh.x;  // direct sum over x[1:]
#pragma unroll
  for (int off = 32; off; off >>= 1) ssh += __shfl_down(ssh, off);
  const float2* s2 = (const float2*)(xS) + (size_t)gw * 64;
  float2 vs = s2[lane];
  float sss = vs.x * vs.x + vs.y * vs.y;
  if (lane == 0) sss -= vs.x * vs.x;
#pragma unroll
  for (int off = 32; off; off >>= 1) sss += __shfl_down(sss, off);
  if (lane == 0) {
    float dv = dinv[gw];
    float nrh = sqrtf(ssh);
    float dist = acoshf(fmaxf(vh.x, 1.0f));
    sc1[gw] = dv * dist / fmaxf(nrh, 1e-12f);
    float nrs = sqrtf(sss);
    float th = acosf(fminf(fmaxf(vs.x, -1.0f), 1.0f));
    sc2[gw] = dv * th / fmaxf(nrs, 1e-12f);
  }
}

// ---------------- W transpose + fp16: Wt[128][384] ----------------
__global__ __launch_bounds__(256) void k_wprep(const float* __restrict__ W,
                                               unsigned short* __restrict__ Wt) {
  int flat = blockIdx.x * 256 + threadIdx.x;
  if (flat >= IND * DD) return;
  int n = flat / IND;
  int k = flat - n * IND;
  Wt[(size_t)n * IND + k] = f2h(W[(size_t)k * DD + n]);
}

// ---- MFMA fp16 GEMM: h = dinv * ([xE | ch*xH | cs*xS] @ W), fp16 out ----
__global__ __launch_bounds__(256) void k_gemm(const float* __restrict__ xE,
                                              const float* __restrict__ xH,
                                              const float* __restrict__ xS,
                                              const float* __restrict__ dinv,
                                              const float* __restrict__ sc1,
                                              const float* __restrict__ sc2,
                                              const unsigned short* __restrict__ Wt,
                                              unsigned short* __restrict__ h) {
  __shared__ unsigned short Ah[64 * 64];  // 8 KB
  int tid = threadIdx.x;
  int lane = tid & 63;
  int wid = tid >> 6;
  int wr = wid >> 1, wc = wid & 1;
  int r0 = wr * 32, c0 = wc * 64;
  int bm0 = blockIdx.x * 64;
  int l15 = lane & 15;
  int lhi = lane >> 4;

  f4v acc[2][4];
#pragma unroll
  for (int m = 0; m < 2; ++m)
#pragma unroll
    for (int nf = 0; nf < 4; ++nf) acc[m][nf] = f4v{0.f, 0.f, 0.f, 0.f};

  for (int kb = 0; kb < IND; kb += 64) {
    int sec = kb >> 7;
    int off = kb & 127;
    const float* __restrict__ src = (sec == 0) ? xE : (sec == 1) ? xH : xS;
#pragma unroll
    for (int it = 0; it < 4; ++it) {
      int flat = tid + it * 256;
      int row = flat >> 4;
      int f4 = flat & 15;
      int node = bm0 + row;
      float4 v = make_float4(0.f, 0.f, 0.f, 0.f);
      float scale = 0.f;
      if (node < NN) {
        v = *(const float4*)&src[(size_t)node * DD + off + f4 * 4];
        scale = (sec == 0) ? dinv[node] : (sec == 1) ? sc1[node] : sc2[node];
      }
      v.x *= scale; v.y *= scale; v.z *= scale; v.w *= scale;
      if (sec > 0 && off == 0 && f4 == 0) v.x = 0.f;  // logmap zero column
      ushort4 o;
      o.x = f2h(v.x); o.y = f2h(v.y); o.z = f2h(v.z); o.w = f2h(v.w);
      int idx = (row * 64 + f4 * 4) ^ ((row & 7) << 3);
      *(ushort4*)&Ah[idx] = o;
    }
    __syncthreads();
#pragma unroll
    for (int ks = 0; ks < 2; ++ks) {
      h8v a[2];
#pragma unroll
      for (int m = 0; m < 2; ++m) {
        int row = r0 + m * 16 + l15;
        int idx = (row * 64 + ks * 32 + lhi * 8) ^ ((row & 7) << 3);
        a[m] = *reinterpret_cast<const h8v*>(&Ah[idx]);
      }
      int kk = kb + ks * 32 + lhi * 8;
#pragma unroll
      for (int nf = 0; nf < 4; ++nf) {
        int n = c0 + nf * 16 + l15;
        h8v b = *reinterpret_cast<const h8v*>(&Wt[(size_t)n * IND + kk]);
#pragma unroll
        for (int m = 0; m < 2; ++m)
          acc[m][nf] = __builtin_amdgcn_mfma_f32_16x16x32_f16(a[m], b, acc[m][nf], 0, 0, 0);
      }
    }
    __syncthreads();
  }
#pragma unroll
  for (int m = 0; m < 2; ++m)
#pragma unroll
    for (int nf = 0; nf < 4; ++nf) {
      int colx = c0 + nf * 16 + l15;
      int rowb = bm0 + r0 + m * 16 + lhi * 4;
#pragma unroll
      for (int j = 0; j < 4; ++j) {
        int node = rowb + j;
        if (node < NN) h[(size_t)node * DD + colx] = f2h(acc[m][nf][j]);
      }
    }
}

// ---------------- normalize class embeddings -> packed fp16 [64][128] --------
__global__ __launch_bounds__(256) void k_cprep(const float* __restrict__ cls,
                                               unsigned int* __restrict__ clsp) {
  int wave = threadIdx.x >> 6, lane = threadIdx.x & 63;
  for (int c = wave; c < CC; c += 4) {
    const float2* r2 = (const float2*)(cls + (size_t)c * DD);
    float2 v = r2[lane];
    float ss = v.x * v.x + v.y * v.y;
#pragma unroll
    for (int off = 32; off; off >>= 1) ss += __shfl_xor(ss, off);
    float inv = 1.0f / fmaxf(sqrtf(ss), 1e-8f);
    clsp[c * 64 + lane] =
        (unsigned int)f2h(v.x * inv) | ((unsigned int)f2h(v.y * inv) << 16);
  }
}

// ---- CSR aggregation (h pre-scaled by dinv) + normalize -> xn fp16 ----
__global__ __launch_bounds__(256) void k_aggn(const unsigned short* __restrict__ h,
                                              const int* __restrict__ rowstart,
                                              const int* __restrict__ col,
                                              const float* __restrict__ dinv,
                                              const float* __restrict__ b,
                                              unsigned int* __restrict__ xn) {
  int node = (blockIdx.x * 256 + threadIdx.x) >> 6;
  int lane = threadIdx.x & 63;
  if (node >= NN) return;

  const unsigned int* h2 = (const unsigned int*)h;
  float dv = dinv[node];
  unsigned int hv = h2[(size_t)node * 64 + lane];
  float ax = hlo(hv), ay = hhi(hv);
  int s = rowstart[node], e = rowstart[node + 1];
  int j = s;
  for (; j + 15 < e; j += 16) {
    int cc[16];
    unsigned int vv[16];
#pragma unroll
    for (int q = 0; q < 16; ++q) cc[q] = col[j + q];
#pragma unroll
    for (int q = 0; q < 16; ++q) vv[q] = h2[(size_t)cc[q] * 64 + lane];
#pragma unroll
    for (int q = 0; q < 16; ++q) {
      ax += hlo(vv[q]);
      ay += hhi(vv[q]);
    }
  }
  for (; j + 3 < e; j += 4) {
    int c0_ = col[j], c1_ = col[j + 1], c2_ = col[j + 2], c3_ = col[j + 3];
    unsigned int v0 = h2[(size_t)c0_ * 64 + lane];
    unsigned int v1 = h2[(size_t)c1_ * 64 + lane];
    unsigned int v2 = h2[(size_t)c2_ * 64 + lane];
    unsigned int v3 = h2[(size_t)c3_ * 64 + lane];
    ax += hlo(v0) + hlo(v1) + hlo(v2) + hlo(v3);
    ay += hhi(v0) + hhi(v1) + hhi(v2) + hhi(v3);
  }
  for (; j < e; ++j) {
    unsigned int v = h2[(size_t)col[j] * 64 + lane];
    ax += hlo(v);
    ay += hhi(v);
  }
  const float2* b2 = (const float2*)b;
  float2 bb = b2[lane];
  float rx = dv * ax + bb.x;
  float ry = dv * ay + bb.y;
  float ss = rx * rx + ry * ry;
#pragma unroll
  for (int off = 32; off; off >>= 1) ss += __shfl_xor(ss, off);
  float inv = 1.0f / fmaxf(sqrtf(ss), 1e-8f);
  xn[(size_t)node * 64 + lane] =
      (unsigned int)f2h(rx * inv) | ((unsigned int)f2h(ry * inv) << 16);
}

// ---- classifier fp16 MFMA GEMM: out = xn @ clsn^T ----
__global__ __launch_bounds__(256) void k_outg(const unsigned short* __restrict__ xn,
                                              const unsigned short* __restrict__ clsp,
                                              float* __restrict__ out) {
  int tid = threadIdx.x;
  int lane = tid & 63;
  int wid = tid >> 6;
  int l15 = lane & 15, lhi = lane >> 4;
  int bm0 = blockIdx.x * 128 + wid * 32;

  f4v acc[2][4];
#pragma unroll
  for (int m = 0; m < 2; ++m)
#pragma unroll
    for (int nf = 0; nf < 4; ++nf) acc[m][nf] = f4v{0.f, 0.f, 0.f, 0.f};

#pragma unroll
  for (int ks = 0; ks < 4; ++ks) {
    h8v a[2];
#pragma unroll
    for (int m = 0; m < 2; ++m) {
      int row = bm0 + m * 16 + l15;
      a[m] = (row < NN)
                 ? *reinterpret_cast<const h8v*>(&xn[(size_t)row * DD + ks * 32 + lhi * 8])
                 : hzero();
    }
#pragma unroll
    for (int nf = 0; nf < 4; ++nf) {
      int n = nf * 16 + l15;
      h8v b = *reinterpret_cast<const h8v*>(&clsp[(size_t)n * DD + ks * 32 + lhi * 8]);
#pragma unroll
      for (int m = 0; m < 2; ++m)
        acc[m][nf] = __builtin_amdgcn_mfma_f32_16x16x32_f16(a[m], b, acc[m][nf], 0, 0, 0);
    }
  }
#pragma unroll
  for (int m = 0; m < 2; ++m)
#pragma unroll
    for (int nf = 0; nf < 4; ++nf) {
      int colx = nf * 16 + l15;
      int rowb = bm0 + m * 16 + lhi * 4;
#pragma unroll
      for (int j = 0; j < 4; ++j) {
        int row = rowb + j;
        if (row < NN) out[(size_t)row * CC + colx] = acc[m][nf][j];
      }
    }
}

extern "C" void kernel_launch(void* const* d_in, const int* in_sizes, int n_in,
                              void* d_out, int out_size, void* d_ws, size_t ws_size,
                              hipStream_t stream) {
  const float* xE = (const float*)d_in[0];
  const float* xH = (const float*)d_in[1];
  const float* xS = (const float*)d_in[2];
  const int* ei = (const int*)d_in[3];
  const float* W = (const float*)d_in[4];
  const float* b = (const float*)d_in[5];
  const float* cls = (const float*)d_in[6];
  float* out = (float*)d_out;

  char* ws = (char*)d_ws;
  size_t off = 0;
  auto alloc = [&](size_t bytes) {
    void* p = ws + off;
    off = (off + bytes + 255) & ~(size_t)255;
    return p;
  };
  unsigned short* h = (unsigned short*)alloc((size_t)NN * DD * 2);
  unsigned int* xn = (unsigned int*)alloc((size_t)NN * 64 * 4);
  float* dinv = (float*)alloc((size_t)NN * 4);
  float* sc1 = (float*)alloc((size_t)NN * 4);
  float* sc2 = (float*)alloc((size_t)NN * 4);
  int* cnt = (int*)alloc((size_t)NN * 4);
  int* rowst = (int*)alloc((size_t)(NN + 1) * 4);
  int* rank = (int*)alloc((size_t)EE * 4);
  int* col = (int*)alloc((size_t)EE * 4);
  unsigned short* Wt = (unsigned short*)alloc((size_t)DD * IND * 2);
  unsigned int* clsp = (unsigned int*)alloc((size_t)CC * 64 * 4);
  int* bsum = (int*)alloc(64 * 4);

  const int* esrc = ei;
  const int* edst = ei + EE;
  const int NB = (NN + 1023) / 1024;

  hipMemsetAsync(cnt, 0, (size_t)NN * 4, stream);
  k_count<<<(EE + 255) / 256, 256, 0, stream>>>(edst, cnt, rank);
  k_scan1<<<NB, 1024, 0, stream>>>(cnt, rowst, dinv, bsum);
  k_scan2<<<1, 64, 0, stream>>>(bsum, rowst, NB);
  k_scan3<<<NB, 1024, 0, stream>>>(rowst, bsum);
  k_place<<<(EE + 255) / 256, 256, 0, stream>>>(esrc, edst, rank, rowst, col);
  k_wprep<<<(IND * DD + 255) / 256, 256, 0, stream>>>(W, Wt);
  k_cprep<<<1, 256, 0, stream>>>(cls, clsp);
  k_scal<<<(NN + 3) / 4, 256, 0, stream>>>(xH, xS, dinv, sc1, sc2);
  k_gemm<<<(NN + 63) / 64, 256, 0, stream>>>(xE, xH, xS, dinv, sc1, sc2, Wt, h);
  k_aggn<<<(NN + 3) / 4, 256, 0, stream>>>(h, rowst, col, dinv, b, xn);
  k_outg<<<(NN + 127) / 128, 256, 0, stream>>>((const unsigned short*)xn,
                                               (const unsigned short*)clsp, out);
}

// Round 11
// 171.939 us; speedup vs baseline: 1.5862x; 1.0021x over previous
//
#include <hip/hip_runtime.h>
#include <hip/hip_fp16.h>
#include <math.h>

#define NN 50000
#define DD 128
#define CC 64
#define EE 800000
#define IND 384

typedef __attribute__((ext_vector_type(8))) _Float16 h8v;
typedef __attribute__((ext_vector_type(4))) float f4v;

static __device__ __forceinline__ unsigned short f2h(float f) {
  _Float16 h = (_Float16)f;
  return *reinterpret_cast<unsigned short*>(&h);
}
static __device__ __forceinline__ float h2f(unsigned short u) {
  _Float16 h = *reinterpret_cast<_Float16*>(&u);
  return (float)h;
}
static __device__ __forceinline__ float hlo(unsigned int u) {
  return h2f((unsigned short)(u & 0xffffu));
}
static __device__ __forceinline__ float hhi(unsigned int u) {
  return h2f((unsigned short)(u >> 16));
}
static __device__ __forceinline__ h8v hzero() {
  h8v v = {0, 0, 0, 0, 0, 0, 0, 0};
  return v;
}

// ---- zero the degree-count array (replaces slow rocclr fillBuffer) ----
__global__ __launch_bounds__(256) void k_zero(int4* __restrict__ cnt4, int n4) {
  int i = blockIdx.x * 256 + threadIdx.x;
  if (i < n4) cnt4[i] = make_int4(0, 0, 0, 0);
}

// ---- edge in-degree count + per-edge rank (atomic return value) ----
__global__ __launch_bounds__(256) void k_count(const int* __restrict__ dst,
                                               int* __restrict__ cnt,
                                               int* __restrict__ rank) {
  int e = blockIdx.x * 256 + threadIdx.x;
  if (e < EE) rank[e] = atomicAdd(&cnt[dst[e]], 1);
}

// ---------------- hierarchical exclusive scan ----------------
__global__ __launch_bounds__(1024) void k_scan1(const int* __restrict__ cnt,
                                                int* __restrict__ rowstart,
                                                float* __restrict__ dinv,
                                                int* __restrict__ bsum) {
  __shared__ int wsum[16];
  int tid = threadIdx.x;
  int wave = tid >> 6, lane = tid & 63;
  int i = blockIdx.x * 1024 + tid;
  int v = (i < NN) ? cnt[i] : 0;
  int x = v;
#pragma unroll
  for (int off = 1; off < 64; off <<= 1) {
    int t = __shfl_up(x, off);
    if (lane >= off) x += t;
  }
  if (lane == 63) wsum[wave] = x;
  __syncthreads();
  if (wave == 0 && lane < 16) {
    int y = wsum[lane];
#pragma unroll
    for (int off = 1; off < 16; off <<= 1) {
      int t = __shfl_up(y, off);
      if (lane >= off) y += t;
    }
    wsum[lane] = y;
  }
  __syncthreads();
  int ex = (wave ? wsum[wave - 1] : 0) + x - v;
  if (i < NN) {
    rowstart[i] = ex;
    dinv[i] = 1.0f / sqrtf((float)(v + 1));
  }
  if (tid == 1023) bsum[blockIdx.x] = wsum[15];
}

__global__ __launch_bounds__(64) void k_scan2(int* __restrict__ bsum,
                                              int* __restrict__ rowstart,
                                              int nb) {
  int lane = threadIdx.x;
  int v = (lane < nb) ? bsum[lane] : 0;
  int x = v;
#pragma unroll
  for (int off = 1; off < 64; off <<= 1) {
    int t = __shfl_up(x, off);
    if (lane >= off) x += t;
  }
  if (lane < nb) bsum[lane] = x - v;
  if (lane == 0) rowstart[NN] = EE;
}

__global__ __launch_bounds__(1024) void k_scan3(int* __restrict__ rowstart,
                                                const int* __restrict__ bsum) {
  int i = blockIdx.x * 1024 + threadIdx.x;
  if (i < NN) rowstart[i] += bsum[blockIdx.x];
}

// ---- CSR placement, atomic-free: p = rowstart[dst] + rank ----
__global__ __launch_bounds__(256) void k_place(const int* __restrict__ src,
                                               const int* __restrict__ dst,
                                               const int* __restrict__ rank,
                                               const int* __restrict__ rowstart,
                                               int* __restrict__ col) {
  int e = blockIdx.x * 256 + threadIdx.x;
  if (e < EE) {
    int d = dst[e];
    col[rowstart[d] + rank[e]] = src[e];
  }
}

// ---- per-node logmap scales with dinv folded: sc1=dinv*ch, sc2=dinv*cs ----
__global__ __launch_bounds__(256) void k_scal(const float* __restrict__ xH,
                                              const float* __restrict__ xS,
                                              const float* __restrict__ dinv,
                                              float* __restrict__ sc1,
                                              float* __restrict__ sc2) {
  int gw = (blockIdx.x * 256 + threadIdx.x) >> 6;
  int lane = threadIdx.x & 63;
  if (gw >= NN) return;
  const float2* h2 = (const float2*)(xH) + (size_t)gw * 64;
  float2 vh = h2[lane];
  float ssh = vh.x * vh.x + vh.y * vh.y;
  if (lane == 0) ssh -= vh.x * vh.x;  // direct sum over x[1:]
#pragma unroll
  for (int off = 32; off; off >>= 1) ssh += __shfl_down(ssh, off);
  const float2* s2 = (const float2*)(xS) + (size_t)gw * 64;
  float2 vs = s2[lane];
  float sss = vs.x * vs.x + vs.y * vs.y;
  if (lane == 0) sss -= vs.x * vs.x;
#pragma unroll
  for (int off = 32; off; off >>= 1) sss += __shfl_down(sss, off);
  if (lane == 0) {
    float dv = dinv[gw];
    float nrh = sqrtf(ssh);
    float dist = acoshf(fmaxf(vh.x, 1.0f));
    sc1[gw] = dv * dist / fmaxf(nrh, 1e-12f);
    float nrs = sqrtf(sss);
    float th = acosf(fminf(fmaxf(vs.x, -1.0f), 1.0f));
    sc2[gw] = dv * th / fmaxf(nrs, 1e-12f);
  }
}

// ---------------- W transpose + fp16: Wt[128][384] ----------------
__global__ __launch_bounds__(256) void k_wprep(const float* __restrict__ W,
                                               unsigned short* __restrict__ Wt) {
  int flat = blockIdx.x * 256 + threadIdx.x;
  if (flat >= IND * DD) return;
  int n = flat / IND;
  int k = flat - n * IND;
  Wt[(size_t)n * IND + k] = f2h(W[(size_t)k * DD + n]);
}

// ---- MFMA fp16 GEMM: h = dinv * ([xE | ch*xH | cs*xS] @ W), fp16 out ----
__global__ __launch_bounds__(256) void k_gemm(const float* __restrict__ xE,
                                              const float* __restrict__ xH,
                                              const float* __restrict__ xS,
                                              const float* __restrict__ dinv,
                                              const float* __restrict__ sc1,
                                              const float* __restrict__ sc2,
                                              const unsigned short* __restrict__ Wt,
                                              unsigned short* __restrict__ h) {
  __shared__ unsigned short Ah[64 * 64];  // 8 KB
  int tid = threadIdx.x;
  int lane = tid & 63;
  int wid = tid >> 6;
  int wr = wid >> 1, wc = wid & 1;
  int r0 = wr * 32, c0 = wc * 64;
  int bm0 = blockIdx.x * 64;
  int l15 = lane & 15;
  int lhi = lane >> 4;

  f4v acc[2][4];
#pragma unroll
  for (int m = 0; m < 2; ++m)
#pragma unroll
    for (int nf = 0; nf < 4; ++nf) acc[m][nf] = f4v{0.f, 0.f, 0.f, 0.f};

  for (int kb = 0; kb < IND; kb += 64) {
    int sec = kb >> 7;
    int off = kb & 127;
    const float* __restrict__ src = (sec == 0) ? xE : (sec == 1) ? xH : xS;
#pragma unroll
    for (int it = 0; it < 4; ++it) {
      int flat = tid + it * 256;
      int row = flat >> 4;
      int f4 = flat & 15;
      int node = bm0 + row;
      float4 v = make_float4(0.f, 0.f, 0.f, 0.f);
      float scale = 0.f;
      if (node < NN) {
        v = *(const float4*)&src[(size_t)node * DD + off + f4 * 4];
        scale = (sec == 0) ? dinv[node] : (sec == 1) ? sc1[node] : sc2[node];
      }
      v.x *= scale; v.y *= scale; v.z *= scale; v.w *= scale;
      if (sec > 0 && off == 0 && f4 == 0) v.x = 0.f;  // logmap zero column
      ushort4 o;
      o.x = f2h(v.x); o.y = f2h(v.y); o.z = f2h(v.z); o.w = f2h(v.w);
      int idx = (row * 64 + f4 * 4) ^ ((row & 7) << 3);
      *(ushort4*)&Ah[idx] = o;
    }
    __syncthreads();
#pragma unroll
    for (int ks = 0; ks < 2; ++ks) {
      h8v a[2];
#pragma unroll
      for (int m = 0; m < 2; ++m) {
        int row = r0 + m * 16 + l15;
        int idx = (row * 64 + ks * 32 + lhi * 8) ^ ((row & 7) << 3);
        a[m] = *reinterpret_cast<const h8v*>(&Ah[idx]);
      }
      int kk = kb + ks * 32 + lhi * 8;
#pragma unroll
      for (int nf = 0; nf < 4; ++nf) {
        int n = c0 + nf * 16 + l15;
        h8v b = *reinterpret_cast<const h8v*>(&Wt[(size_t)n * IND + kk]);
#pragma unroll
        for (int m = 0; m < 2; ++m)
          acc[m][nf] = __builtin_amdgcn_mfma_f32_16x16x32_f16(a[m], b, acc[m][nf], 0, 0, 0);
      }
    }
    __syncthreads();
  }
#pragma unroll
  for (int m = 0; m < 2; ++m)
#pragma unroll
    for (int nf = 0; nf < 4; ++nf) {
      int colx = c0 + nf * 16 + l15;
      int rowb = bm0 + r0 + m * 16 + lhi * 4;
#pragma unroll
      for (int j = 0; j < 4; ++j) {
        int node = rowb + j;
        if (node < NN) h[(size_t)node * DD + colx] = f2h(acc[m][nf][j]);
      }
    }
}

// ---------------- normalize class embeddings -> packed fp16 [64][128] --------
__global__ __launch_bounds__(256) void k_cprep(const float* __restrict__ cls,
                                               unsigned int* __restrict__ clsp) {
  int wave = threadIdx.x >> 6, lane = threadIdx.x & 63;
  for (int c = wave; c < CC; c += 4) {
    const float2* r2 = (const float2*)(cls + (size_t)c * DD);
    float2 v = r2[lane];
    float ss = v.x * v.x + v.y * v.y;
#pragma unroll
    for (int off = 32; off; off >>= 1) ss += __shfl_xor(ss, off);
    float inv = 1.0f / fmaxf(sqrtf(ss), 1e-8f);
    clsp[c * 64 + lane] =
        (unsigned int)f2h(v.x * inv) | ((unsigned int)f2h(v.y * inv) << 16);
  }
}

// ---- CSR aggregation (h pre-scaled by dinv) + normalize -> xn fp16 ----
__global__ __launch_bounds__(256) void k_aggn(const unsigned short* __restrict__ h,
                                              const int* __restrict__ rowstart,
                                              const int* __restrict__ col,
                                              const float* __restrict__ dinv,
                                              const float* __restrict__ b,
                                              unsigned int* __restrict__ xn) {
  int node = (blockIdx.x * 256 + threadIdx.x) >> 6;
  int lane = threadIdx.x & 63;
  if (node >= NN) return;

  const unsigned int* h2 = (const unsigned int*)h;
  float dv = dinv[node];
  unsigned int hv = h2[(size_t)node * 64 + lane];
  float ax = hlo(hv), ay = hhi(hv);
  int s = rowstart[node], e = rowstart[node + 1];
  int j = s;
  for (; j + 15 < e; j += 16) {
    int cc[16];
    unsigned int vv[16];
#pragma unroll
    for (int q = 0; q < 16; ++q) cc[q] = col[j + q];
#pragma unroll
    for (int q = 0; q < 16; ++q) vv[q] = h2[(size_t)cc[q] * 64 + lane];
#pragma unroll
    for (int q = 0; q < 16; ++q) {
      ax += hlo(vv[q]);
      ay += hhi(vv[q]);
    }
  }
  for (; j + 3 < e; j += 4) {
    int c0_ = col[j], c1_ = col[j + 1], c2_ = col[j + 2], c3_ = col[j + 3];
    unsigned int v0 = h2[(size_t)c0_ * 64 + lane];
    unsigned int v1 = h2[(size_t)c1_ * 64 + lane];
    unsigned int v2 = h2[(size_t)c2_ * 64 + lane];
    unsigned int v3 = h2[(size_t)c3_ * 64 + lane];
    ax += hlo(v0) + hlo(v1) + hlo(v2) + hlo(v3);
    ay += hhi(v0) + hhi(v1) + hhi(v2) + hhi(v3);
  }
  for (; j < e; ++j) {
    unsigned int v = h2[(size_t)col[j] * 64 + lane];
    ax += hlo(v);
    ay += hhi(v);
  }
  const float2* b2 = (const float2*)b;
  float2 bb = b2[lane];
  float rx = dv * ax + bb.x;
  float ry = dv * ay + bb.y;
  float ss = rx * rx + ry * ry;
#pragma unroll
  for (int off = 32; off; off >>= 1) ss += __shfl_xor(ss, off);
  float inv = 1.0f / fmaxf(sqrtf(ss), 1e-8f);
  xn[(size_t)node * 64 + lane] =
      (unsigned int)f2h(rx * inv) | ((unsigned int)f2h(ry * inv) << 16);
}

// ---- classifier fp16 MFMA GEMM: out = xn @ clsn^T ----
__global__ __launch_bounds__(256) void k_outg(const unsigned short* __restrict__ xn,
                                              const unsigned short* __restrict__ clsp,
                                              float* __restrict__ out) {
  int tid = threadIdx.x;
  int lane = tid & 63;
  int wid = tid >> 6;
  int l15 = lane & 15, lhi = lane >> 4;
  int bm0 = blockIdx.x * 128 + wid * 32;

  f4v acc[2][4];
#pragma unroll
  for (int m = 0; m < 2; ++m)
#pragma unroll
    for (int nf = 0; nf < 4; ++nf) acc[m][nf] = f4v{0.f, 0.f, 0.f, 0.f};

#pragma unroll
  for (int ks = 0; ks < 4; ++ks) {
    h8v a[2];
#pragma unroll
    for (int m = 0; m < 2; ++m) {
      int row = bm0 + m * 16 + l15;
      a[m] = (row < NN)
                 ? *reinterpret_cast<const h8v*>(&xn[(size_t)row * DD + ks * 32 + lhi * 8])
                 : hzero();
    }
#pragma unroll
    for (int nf = 0; nf < 4; ++nf) {
      int n = nf * 16 + l15;
      h8v b = *reinterpret_cast<const h8v*>(&clsp[(size_t)n * DD + ks * 32 + lhi * 8]);
#pragma unroll
      for (int m = 0; m < 2; ++m)
        acc[m][nf] = __builtin_amdgcn_mfma_f32_16x16x32_f16(a[m], b, acc[m][nf], 0, 0, 0);
    }
  }
#pragma unroll
  for (int m = 0; m < 2; ++m)
#pragma unroll
    for (int nf = 0; nf < 4; ++nf) {
      int colx = nf * 16 + l15;
      int rowb = bm0 + m * 16 + lhi * 4;
#pragma unroll
      for (int j = 0; j < 4; ++j) {
        int row = rowb + j;
        if (row < NN) out[(size_t)row * CC + colx] = acc[m][nf][j];
      }
    }
}

extern "C" void kernel_launch(void* const* d_in, const int* in_sizes, int n_in,
                              void* d_out, int out_size, void* d_ws, size_t ws_size,
                              hipStream_t stream) {
  const float* xE = (const float*)d_in[0];
  const float* xH = (const float*)d_in[1];
  const float* xS = (const float*)d_in[2];
  const int* ei = (const int*)d_in[3];
  const float* W = (const float*)d_in[4];
  const float* b = (const float*)d_in[5];
  const float* cls = (const float*)d_in[6];
  float* out = (float*)d_out;

  char* ws = (char*)d_ws;
  size_t off = 0;
  auto alloc = [&](size_t bytes) {
    void* p = ws + off;
    off = (off + bytes + 255) & ~(size_t)255;
    return p;
  };
  unsigned short* h = (unsigned short*)alloc((size_t)NN * DD * 2);
  unsigned int* xn = (unsigned int*)alloc((size_t)NN * 64 * 4);
  float* dinv = (float*)alloc((size_t)NN * 4);
  float* sc1 = (float*)alloc((size_t)NN * 4);
  float* sc2 = (float*)alloc((size_t)NN * 4);
  int* cnt = (int*)alloc((size_t)(NN + 16) * 4);  // padded to int4 multiple
  int* rowst = (int*)alloc((size_t)(NN + 1) * 4);
  int* rank = (int*)alloc((size_t)EE * 4);
  int* col = (int*)alloc((size_t)EE * 4);
  unsigned short* Wt = (unsigned short*)alloc((size_t)DD * IND * 2);
  unsigned int* clsp = (unsigned int*)alloc((size_t)CC * 64 * 4);
  int* bsum = (int*)alloc(64 * 4);

  const int* esrc = ei;
  const int* edst = ei + EE;
  const int NB = (NN + 1023) / 1024;
  const int N4 = (NN + 3) / 4;  // 12500 int4s

  k_zero<<<(N4 + 255) / 256, 256, 0, stream>>>((int4*)cnt, N4);
  k_count<<<(EE + 255) / 256, 256, 0, stream>>>(edst, cnt, rank);
  k_scan1<<<NB, 1024, 0, stream>>>(cnt, rowst, dinv, bsum);
  k_scan2<<<1, 64, 0, stream>>>(bsum, rowst, NB);
  k_scan3<<<NB, 1024, 0, stream>>>(rowst, bsum);
  k_place<<<(EE + 255) / 256, 256, 0, stream>>>(esrc, edst, rank, rowst, col);
  k_wprep<<<(IND * DD + 255) / 256, 256, 0, stream>>>(W, Wt);
  k_cprep<<<1, 256, 0, stream>>>(cls, clsp);
  k_scal<<<(NN + 3) / 4, 256, 0, stream>>>(xH, xS, dinv, sc1, sc2);
  k_gemm<<<(NN + 63) / 64, 256, 0, stream>>>(xE, xH, xS, dinv, sc1, sc2, Wt, h);
  k_aggn<<<(NN + 3) / 4, 256, 0, stream>>>(h, rowst, col, dinv, b, xn);
  k_outg<<<(NN + 127) / 128, 256, 0, stream>>>((const unsigned short*)xn,
                                               (const unsigned short*)clsp, out);
}